// Round 8
// baseline (97.627 us; speedup 1.0000x reference)
//
#include <hip/hip_runtime.h>
#include <hip/hip_bf16.h>

#define NB 8192   // batch
#define ND 512    // feature dim
#define NC 512    // num classes
#define MARGIN_F 1.0f
#define BIGF 3.0e38f

typedef __attribute__((ext_vector_type(8))) short bf16x8;
typedef __attribute__((ext_vector_type(4))) float f32x4;

__device__ __forceinline__ unsigned fkey(float f) {
    unsigned u = __float_as_uint(f);
    unsigned mask = (u & 0x80000000u) ? 0xFFFFFFFFu : 0x80000000u;
    return u ^ mask;
}
__device__ __forceinline__ float finv(unsigned k) {
    unsigned mask = (k & 0x80000000u) ? 0x80000000u : 0xFFFFFFFFu;
    return __uint_as_float(k ^ mask);
}
__device__ __forceinline__ unsigned short f2bf(float f) {
    __hip_bfloat16 h = __float2bfloat16(f);
    return __builtin_bit_cast(unsigned short, h);
}

#define GLOAD_LDS16(g, l)                                                    \
    __builtin_amdgcn_global_load_lds(                                        \
        (const __attribute__((address_space(1))) void*)(g),                  \
        (__attribute__((address_space(3))) void*)(l), 16, 0, 0)

// -------------------------------------------------------------------------
// k0: fp32->bf16 convert (inputs + centers), row/center sqnorms, negmin
//     init, class histogram. grid = 2177 x 256. (R2-proven structure.)
// -------------------------------------------------------------------------
__global__ __launch_bounds__(256) void k0_prep(
    const float* __restrict__ inputs, const int* __restrict__ targets,
    const float* __restrict__ centers,
    unsigned short* __restrict__ inB, unsigned short* __restrict__ cenB,
    float* __restrict__ rsq, float* __restrict__ csq,
    unsigned* __restrict__ counts, unsigned* __restrict__ negmin)
{
    const int bid = blockIdx.x;
    const int tid = threadIdx.x;

    if (bid == 2176) {   // histogram block
        __shared__ unsigned hist[NC];
        for (int i = tid; i < NC; i += 256) hist[i] = 0u;
        __syncthreads();
        for (int i = tid; i < NB; i += 256) atomicAdd(&hist[targets[i]], 1u);
        __syncthreads();
        for (int i = tid; i < NC; i += 256) counts[i] = hist[i];
        return;
    }

    const int wave = tid >> 6, lane = tid & 63;
    const float* src;
    unsigned short* dst;
    float* sqdst;
    int row;
    bool is_input = (bid < 2048);
    if (is_input) {
        row   = bid * 4 + wave;
        src   = inputs + (size_t)row * ND;
        dst   = inB + (size_t)row * ND;
        sqdst = rsq + row;
    } else {
        row   = (bid - 2048) * 4 + wave;
        src   = centers + (size_t)row * ND;
        dst   = cenB + (size_t)row * ND;
        sqdst = csq + row;
    }

    float4 v1 = ((const float4*)src)[lane];
    float4 v2 = ((const float4*)src)[lane + 64];
    float s = v1.x*v1.x + v1.y*v1.y + v1.z*v1.z + v1.w*v1.w
            + v2.x*v2.x + v2.y*v2.y + v2.z*v2.z + v2.w*v2.w;

    ushort4 o1, o2;
    o1.x = f2bf(v1.x); o1.y = f2bf(v1.y); o1.z = f2bf(v1.z); o1.w = f2bf(v1.w);
    o2.x = f2bf(v2.x); o2.y = f2bf(v2.y); o2.z = f2bf(v2.z); o2.w = f2bf(v2.w);
    ((ushort4*)dst)[lane]      = o1;
    ((ushort4*)dst)[lane + 64] = o2;

    #pragma unroll
    for (int off = 32; off > 0; off >>= 1) s += __shfl_down(s, off);
    if (lane == 0) {
        *sqdst = s;
        if (is_input) negmin[row] = 0xFFFFFFFFu;
    }
}

// -------------------------------------------------------------------------
// k2: bf16 MFMA GEMM + masked-min epilogue. BM=128, BN=64, BK=64,
// 256 threads = 4 waves (2 row-halves x 2 col-halves, wave tile 64x32).
// LDS staged in FRAGMENT ORDER via global_load_lds: each 16x32 subtile's
// lane-l slot holds (row=l&15, kchunk=l>>4), so frag ds_read_b128 is
// exactly base + lane*16B -> zero bank conflicts, no padding.
// grid = 512 blocks (rtile = bid&63 -> XCD-local A reuse), 2 blocks/CU.
// -------------------------------------------------------------------------
__global__ __launch_bounds__(256) void k2_mfma(
    const unsigned short* __restrict__ Ain, const unsigned short* __restrict__ cenB,
    const int* __restrict__ targets, const unsigned* __restrict__ counts,
    const float* __restrict__ csq,
    unsigned* __restrict__ negmin, float* __restrict__ apval)
{
    // A: 16 chunks (8 row-groups x 2 k-halves), chunk = (rg*2+kh)*512 shorts.
    // B:  8 chunks (4 col-groups x 2 k-halves), chunk = (cg*2+kh)*512 shorts.
    __shared__ __align__(16) unsigned short As[16 * 512];   // 16 KB
    __shared__ __align__(16) unsigned short Bs[8 * 512];    //  8 KB
    __shared__ int      tgtL[128];
    __shared__ float    csqL[64];
    __shared__ unsigned ldsmin[128];

    const int tid  = threadIdx.x;
    const int w    = tid >> 6;
    const int lane = tid & 63;
    const int wm   = w >> 1;      // 0..1 : 64-row half
    const int wn   = w & 1;       // 0..1 : 32-col half
    const int ln   = lane & 15;
    const int kc8  = (lane >> 4) * 8;   // staging k-offset within 32-k chunk

    const int bid   = blockIdx.x;
    const int rbase = (bid & 63) * 128;
    const int cbase = (bid >> 6) * 64;

    if (tid < 128) { tgtL[tid] = targets[rbase + tid]; ldsmin[tid] = 0xFFFFFFFFu; }
    if (tid < 64) {
        const int c = cbase + tid;
        csqL[tid] = (counts[c] > 0u) ? csq[c] : BIGF;   // empty class never wins min
    }

    // Staging assignment: wave w stages A chunks {4w..4w+3} and B chunks
    // {2w, 2w+1}. Chunk id = rg*2+kh (A) / cg*2+kh (B).
    const unsigned short* gAp[4];
    unsigned short*       lAp[4];
    #pragma unroll
    for (int t = 0; t < 4; ++t) {
        const int cid = 4 * w + t;
        const int rg = cid >> 1, kh = cid & 1;
        gAp[t] = Ain + (size_t)(rbase + rg * 16 + ln) * ND + kh * 32 + kc8;
        lAp[t] = &As[cid * 512];
    }
    const unsigned short* gBp[2];
    unsigned short*       lBp[2];
    #pragma unroll
    for (int t = 0; t < 2; ++t) {
        const int cid = 2 * w + t;          // cg = w, kh = t
        gBp[t] = cenB + (size_t)(cbase + w * 16 + ln) * ND + t * 32 + kc8;
        lBp[t] = &Bs[cid * 512];
    }

    f32x4 acc[4][2] = {};   // 4 row-frags x 2 col-frags of 16x16

    for (int kb = 0; kb < ND; kb += 64) {
        __syncthreads();                       // prev iter's ds_reads done
        #pragma unroll
        for (int t = 0; t < 4; ++t) GLOAD_LDS16(gAp[t] + kb, lAp[t]);
        #pragma unroll
        for (int t = 0; t < 2; ++t) GLOAD_LDS16(gBp[t] + kb, lBp[t]);
        __syncthreads();                       // drains vmcnt -> tile visible

        #pragma unroll
        for (int ks = 0; ks < 2; ++ks) {
            bf16x8 a[4], b[2];
            #pragma unroll
            for (int i = 0; i < 4; ++i)
                a[i] = *(const bf16x8*)&As[((wm * 4 + i) * 2 + ks) * 512 + lane * 8];
            #pragma unroll
            for (int j = 0; j < 2; ++j)
                b[j] = *(const bf16x8*)&Bs[((wn * 2 + j) * 2 + ks) * 512 + lane * 8];
            #pragma unroll
            for (int i = 0; i < 4; ++i)
                #pragma unroll
                for (int j = 0; j < 2; ++j)
                    acc[i][j] = __builtin_amdgcn_mfma_f32_16x16x32_bf16(a[i], b[j], acc[i][j], 0, 0, 0);
        }
    }

    // Epilogue. C/D layout: col = lane&15, row = (lane>>4)*4 + reg.
    const int qd = lane >> 4;
    #pragma unroll
    for (int i = 0; i < 4; ++i) {
        #pragma unroll
        for (int r = 0; r < 4; ++r) {
            const int rlocal = wm * 64 + i * 16 + qd * 4 + r;
            const int grow   = rbase + rlocal;
            const int tr     = tgtL[rlocal];
            float m = BIGF;
            #pragma unroll
            for (int j = 0; j < 2; ++j) {
                const int clocal = wn * 32 + j * 16 + ln;
                const float val = csqL[clocal] - 2.0f * acc[i][j][r];
                if (cbase + clocal == tr) {
                    apval[grow] = val;                 // exactly one writer per row
                } else {
                    m = fminf(m, val);
                }
            }
            #pragma unroll
            for (int off = 1; off < 16; off <<= 1)     // min over 16 cols in-wave
                m = fminf(m, __shfl_xor(m, off));
            if (ln == 0) atomicMin(&ldsmin[rlocal], fkey(m));
        }
    }
    __syncthreads();
    if (tid < 128) {
        unsigned v = ldsmin[tid];
        if (v != 0xFFFFFFFFu) atomicMin(&negmin[rbase + tid], v);
    }
}

// -------------------------------------------------------------------------
// k3: finalize + reduce, single block (reads only 96 KB of per-row scalars).
// -------------------------------------------------------------------------
__global__ __launch_bounds__(1024) void k3_final(
    const float* __restrict__ rsq, const unsigned* __restrict__ negmin,
    const float* __restrict__ apval, float* __restrict__ out)
{
    __shared__ float sl[1024];
    __shared__ float sp[1024];
    const int tid = threadIdx.x;
    float a = 0.0f, p = 0.0f;
    for (int r = tid; r < NB; r += 1024) {
        float s  = rsq[r];
        float an = sqrtf(fmaxf(s + finv(negmin[r]), 1e-12f));
        float ap = sqrtf(fmaxf(s + apval[r], 1e-12f));
        a += fmaxf(0.0f, ap - an + MARGIN_F);
        p += (an > ap) ? 1.0f : 0.0f;
    }
    sl[tid] = a; sp[tid] = p;
    __syncthreads();
    #pragma unroll
    for (int s = 512; s > 0; s >>= 1) {
        if (tid < s) { sl[tid] += sl[tid + s]; sp[tid] += sp[tid + s]; }
        __syncthreads();
    }
    if (tid == 0) {
        out[0] = sl[0] / (float)NB;
        out[1] = sp[0] / (float)NB;
    }
}

extern "C" void kernel_launch(void* const* d_in, const int* in_sizes, int n_in,
                              void* d_out, int out_size, void* d_ws, size_t ws_size,
                              hipStream_t stream) {
    const float* inputs  = (const float*)d_in[0];
    const int*   targets = (const int*)d_in[1];
    const float* centers = (const float*)d_in[2];
    float* out = (float*)d_out;

    // ws layout (bytes):
    char* wp = (char*)d_ws;
    unsigned short* inB    = (unsigned short*)(wp);             // 8192*512*2 = 8388608
    unsigned short* cenB   = (unsigned short*)(wp + 8388608);   // 512*512*2  = 524288
    float*          rsq    = (float*)(wp + 8912896);            // 8192*4
    float*          csqv   = (float*)(wp + 8945664);            // 512*4
    unsigned*       counts = (unsigned*)(wp + 8947712);         // 512*4
    unsigned*       negmin = (unsigned*)(wp + 8949760);         // 8192*4
    float*          apval  = (float*)(wp + 8982528);            // 8192*4

    k0_prep<<<2177, 256, 0, stream>>>(inputs, targets, centers,
                                      inB, cenB, rsq, csqv, counts, negmin);
    k2_mfma<<<512, 256, 0, stream>>>(inB, cenB, targets, counts, csqv,
                                     negmin, apval);
    k3_final<<<1, 1024, 0, stream>>>(rsq, negmin, apval, out);
}

// Round 10
// 97.534 us; speedup vs baseline: 1.0010x; 1.0010x over previous
//
#include <hip/hip_runtime.h>
#include <hip/hip_bf16.h>

#define NB 8192   // batch
#define ND 512    // feature dim
#define NC 512    // num classes
#define NCT 8     // number of column tiles (NC / 64) -- R9 bug: was 16
#define MARGIN_F 1.0f
#define BIGF 3.0e38f

typedef __attribute__((ext_vector_type(8))) short bf16x8;
typedef __attribute__((ext_vector_type(4))) float f32x4;

__device__ __forceinline__ unsigned fkey(float f) {
    unsigned u = __float_as_uint(f);
    unsigned mask = (u & 0x80000000u) ? 0xFFFFFFFFu : 0x80000000u;
    return u ^ mask;
}
__device__ __forceinline__ float finv(unsigned k) {
    unsigned mask = (k & 0x80000000u) ? 0x80000000u : 0xFFFFFFFFu;
    return __uint_as_float(k ^ mask);
}
__device__ __forceinline__ unsigned short f2bf(float f) {
    __hip_bfloat16 h = __float2bfloat16(f);
    return __builtin_bit_cast(unsigned short, h);
}

#define GLOAD_LDS16(g, l)                                                    \
    __builtin_amdgcn_global_load_lds(                                        \
        (const __attribute__((address_space(1))) void*)(g),                  \
        (__attribute__((address_space(3))) void*)(l), 16, 0, 0)

// -------------------------------------------------------------------------
// k0: fp32->bf16 convert (inputs + centers), row/center sqnorms, class
//     histogram. grid = 2177 x 256.
// -------------------------------------------------------------------------
__global__ __launch_bounds__(256) void k0_prep(
    const float* __restrict__ inputs, const int* __restrict__ targets,
    const float* __restrict__ centers,
    unsigned short* __restrict__ inB, unsigned short* __restrict__ cenB,
    float* __restrict__ rsq, float* __restrict__ csq,
    unsigned* __restrict__ counts)
{
    const int bid = blockIdx.x;
    const int tid = threadIdx.x;

    if (bid == 2176) {   // histogram block
        __shared__ unsigned hist[NC];
        for (int i = tid; i < NC; i += 256) hist[i] = 0u;
        __syncthreads();
        for (int i = tid; i < NB; i += 256) atomicAdd(&hist[targets[i]], 1u);
        __syncthreads();
        for (int i = tid; i < NC; i += 256) counts[i] = hist[i];
        return;
    }

    const int wave = tid >> 6, lane = tid & 63;
    const float* src;
    unsigned short* dst;
    float* sqdst;
    int row;
    bool is_input = (bid < 2048);
    if (is_input) {
        row   = bid * 4 + wave;
        src   = inputs + (size_t)row * ND;
        dst   = inB + (size_t)row * ND;
        sqdst = rsq + row;
    } else {
        row   = (bid - 2048) * 4 + wave;
        src   = centers + (size_t)row * ND;
        dst   = cenB + (size_t)row * ND;
        sqdst = csq + row;
    }

    float4 v1 = ((const float4*)src)[lane];
    float4 v2 = ((const float4*)src)[lane + 64];
    float s = v1.x*v1.x + v1.y*v1.y + v1.z*v1.z + v1.w*v1.w
            + v2.x*v2.x + v2.y*v2.y + v2.z*v2.z + v2.w*v2.w;

    ushort4 o1, o2;
    o1.x = f2bf(v1.x); o1.y = f2bf(v1.y); o1.z = f2bf(v1.z); o1.w = f2bf(v1.w);
    o2.x = f2bf(v2.x); o2.y = f2bf(v2.y); o2.z = f2bf(v2.z); o2.w = f2bf(v2.w);
    ((ushort4*)dst)[lane]      = o1;
    ((ushort4*)dst)[lane + 64] = o2;

    #pragma unroll
    for (int off = 32; off > 0; off >>= 1) s += __shfl_down(s, off);
    if (lane == 0) *sqdst = s;
}

// -------------------------------------------------------------------------
// k2: bf16 MFMA GEMM + masked-min epilogue. BM=BN=64, BK=64, 256 threads =
// 4 waves in 2x2 (wave tile 32x32). grid = 1024 blocks = 128 rtiles x 8
// ctiles (rtile = bid&127 -> all 8 ctile-blocks of a rtile on one XCD) =
// 4 blocks/CU for cross-block latency hiding.
// LDS staged in FRAGMENT ORDER via global_load_lds (conflict-free b128).
// Per-rtile results go to partmin via PLAIN stores (no global atomics).
// -------------------------------------------------------------------------
__global__ __launch_bounds__(256) void k2_mfma(
    const unsigned short* __restrict__ Ain, const unsigned short* __restrict__ cenB,
    const int* __restrict__ targets, const unsigned* __restrict__ counts,
    const float* __restrict__ csq,
    float* __restrict__ partmin, float* __restrict__ apval)
{
    // A: 8 chunks (4 row-groups x 2 k-halves); B: 8 chunks (4 col-groups x 2).
    // Chunk = 16 rows x 32 k in fragment order: slot lane*8 shorts holds
    // (row = lane&15, k = (lane>>4)*8 ..+8).
    __shared__ __align__(16) unsigned short As[8 * 512];   // 8 KB
    __shared__ __align__(16) unsigned short Bs[8 * 512];   // 8 KB
    __shared__ int      tgtL[64];
    __shared__ float    csqL[64];
    __shared__ unsigned ldsmin[64];

    const int tid  = threadIdx.x;
    const int w    = tid >> 6;
    const int lane = tid & 63;
    const int wm   = w >> 1;      // 0..1 : 32-row half
    const int wn   = w & 1;       // 0..1 : 32-col half
    const int ln   = lane & 15;
    const int qd   = lane >> 4;

    const int bid   = blockIdx.x;
    const int rbase = (bid & 127) * 64;   // rtile fastest -> rtile%8 pins XCD
    const int ct    = bid >> 7;           // 0..7
    const int cbase = ct * 64;

    if (tid < 64) {
        tgtL[tid]   = targets[rbase + tid];
        const int c = cbase + tid;
        csqL[tid]   = (counts[c] > 0u) ? csq[c] : BIGF;  // empty class never wins
        ldsmin[tid] = 0xFFFFFFFFu;
    }

    // Staging: wave w stages A chunks {2w, 2w+1} (rg=w, kh=t) and likewise B.
    const unsigned short* gAp[2];
    const unsigned short* gBp[2];
    unsigned short *lAp[2], *lBp[2];
    #pragma unroll
    for (int t = 0; t < 2; ++t) {
        const int cid = 2 * w + t;
        gAp[t] = Ain  + (size_t)(rbase + w * 16 + ln) * ND + t * 32 + qd * 8;
        gBp[t] = cenB + (size_t)(cbase + w * 16 + ln) * ND + t * 32 + qd * 8;
        lAp[t] = &As[cid * 512];
        lBp[t] = &Bs[cid * 512];
    }

    f32x4 acc[2][2] = {};   // 2 row-frags x 2 col-frags of 16x16

    for (int kb = 0; kb < ND; kb += 64) {
        __syncthreads();                       // prev iter's ds_reads done
        #pragma unroll
        for (int t = 0; t < 2; ++t) {
            GLOAD_LDS16(gAp[t] + kb, lAp[t]);
            GLOAD_LDS16(gBp[t] + kb, lBp[t]);
        }
        __syncthreads();                       // drains vmcnt -> tile visible

        #pragma unroll
        for (int ks = 0; ks < 2; ++ks) {
            bf16x8 a[2], b[2];
            #pragma unroll
            for (int i = 0; i < 2; ++i)
                a[i] = *(const bf16x8*)&As[((wm * 2 + i) * 2 + ks) * 512 + lane * 8];
            #pragma unroll
            for (int j = 0; j < 2; ++j)
                b[j] = *(const bf16x8*)&Bs[((wn * 2 + j) * 2 + ks) * 512 + lane * 8];
            #pragma unroll
            for (int i = 0; i < 2; ++i)
                #pragma unroll
                for (int j = 0; j < 2; ++j)
                    acc[i][j] = __builtin_amdgcn_mfma_f32_16x16x32_bf16(a[i], b[j], acc[i][j], 0, 0, 0);
        }
    }

    // Epilogue. C/D layout: col = lane&15, row = (lane>>4)*4 + reg.
    #pragma unroll
    for (int i = 0; i < 2; ++i) {
        #pragma unroll
        for (int r = 0; r < 4; ++r) {
            const int rlocal = wm * 32 + i * 16 + qd * 4 + r;
            const int grow   = rbase + rlocal;
            const int tr     = tgtL[rlocal];
            float m = BIGF;
            #pragma unroll
            for (int j = 0; j < 2; ++j) {
                const int clocal = wn * 32 + j * 16 + ln;
                const float val = csqL[clocal] - 2.0f * acc[i][j][r];
                if (cbase + clocal == tr) {
                    apval[grow] = val;                 // exactly one writer per row
                } else {
                    m = fminf(m, val);
                }
            }
            #pragma unroll
            for (int off = 1; off < 16; off <<= 1)     // min over 16 cols in-wave
                m = fminf(m, __shfl_xor(m, off));
            if (ln == 0) atomicMin(&ldsmin[rlocal], fkey(m));
        }
    }
    __syncthreads();
    if (tid < 64)
        partmin[(size_t)(rbase + tid) * NCT + ct] = finv(ldsmin[tid]);  // plain store
}

// -------------------------------------------------------------------------
// k3: finalize + reduce, single block. partmin rows are contiguous 8-float
// runs -> two float4 loads per row, fully coalesced.
// -------------------------------------------------------------------------
__global__ __launch_bounds__(1024) void k3_final(
    const float* __restrict__ rsq, const float* __restrict__ partmin,
    const float* __restrict__ apval, float* __restrict__ out)
{
    __shared__ float sl[1024];
    __shared__ float sp[1024];
    const int tid = threadIdx.x;
    float a = 0.0f, p = 0.0f;
    #pragma unroll
    for (int it = 0; it < NB / 1024; ++it) {
        const int r = it * 1024 + tid;
        const float4* pm = (const float4*)&partmin[(size_t)r * NCT];
        float4 m0 = pm[0], m1 = pm[1];
        float m = fminf(fminf(fminf(m0.x, m0.y), fminf(m0.z, m0.w)),
                        fminf(fminf(m1.x, m1.y), fminf(m1.z, m1.w)));
        float s  = rsq[r];
        float an = sqrtf(fmaxf(s + m,        1e-12f));
        float ap = sqrtf(fmaxf(s + apval[r], 1e-12f));
        a += fmaxf(0.0f, ap - an + MARGIN_F);
        p += (an > ap) ? 1.0f : 0.0f;
    }
    sl[tid] = a; sp[tid] = p;
    __syncthreads();
    #pragma unroll
    for (int s = 512; s > 0; s >>= 1) {
        if (tid < s) { sl[tid] += sl[tid + s]; sp[tid] += sp[tid + s]; }
        __syncthreads();
    }
    if (tid == 0) {
        out[0] = sl[0] / (float)NB;
        out[1] = sp[0] / (float)NB;
    }
}

extern "C" void kernel_launch(void* const* d_in, const int* in_sizes, int n_in,
                              void* d_out, int out_size, void* d_ws, size_t ws_size,
                              hipStream_t stream) {
    const float* inputs  = (const float*)d_in[0];
    const int*   targets = (const int*)d_in[1];
    const float* centers = (const float*)d_in[2];
    float* out = (float*)d_out;

    // ws layout (bytes):
    char* wp = (char*)d_ws;
    unsigned short* inB     = (unsigned short*)(wp);             // 8192*512*2 = 8388608
    unsigned short* cenB    = (unsigned short*)(wp + 8388608);   // 512*512*2  = 524288
    float*          rsq     = (float*)(wp + 8912896);            // 8192*4
    float*          csqv    = (float*)(wp + 8945664);            // 512*4
    unsigned*       counts  = (unsigned*)(wp + 8947712);         // 512*4
    float*          apval   = (float*)(wp + 8949760);            // 8192*4
    float*          partmin = (float*)(wp + 8982528);            // 8192*8*4 = 262144

    k0_prep<<<2177, 256, 0, stream>>>(inputs, targets, centers,
                                      inB, cenB, rsq, csqv, counts);
    k2_mfma<<<1024, 256, 0, stream>>>(inB, cenB, targets, counts, csqv,
                                      partmin, apval);
    k3_final<<<1, 1024, 0, stream>>>(rsq, partmin, apval, out);
}